// Round 1
// baseline (5456.043 us; speedup 1.0000x reference)
//
#include <hip/hip_runtime.h>
#include <cstdint>
#include <cstddef>

#define T_LEN 4096
#define C_DIM 256
#define B_DIM 8
#define K_TOP 4

__device__ __forceinline__ float gelu_exact(float x) {
    return 0.5f * x * (1.0f + erff(x * 0.70710678118654752f));
}

// ------------------------------------------------------------------
// out = x   (fp32, float4 vectorized)
// ------------------------------------------------------------------
__global__ __launch_bounds__(256) void copy_x_kernel(const float4* __restrict__ x,
                                                     float4* __restrict__ out) {
    size_t i = (size_t)blockIdx.x * 256 + threadIdx.x;
    out[i] = x[i];
}

// ------------------------------------------------------------------
// Per-(b,c) 4096-pt radix-2 DIT FFT in LDS; write |X_f| for f=1..2048
// mags layout: [b][c][2048]  (coalesced writes, coalesced reduce reads)
// ------------------------------------------------------------------
__global__ __launch_bounds__(256) void fft_mag_kernel(const float* __restrict__ x,
                                                      float* __restrict__ mags) {
    const int bx = blockIdx.x;
    const int b = bx >> 8;
    const int c = bx & 255;
    const int tid = threadIdx.x;

    __shared__ __align__(16) float re[4096];
    __shared__ __align__(16) float im[4096];
    __shared__ __align__(16) float twr[2048];
    __shared__ __align__(16) float twi[2048];

    // twiddle table: W[u] = exp(-2*pi*i*u/4096)
    for (int u = tid; u < 2048; u += 256) {
        float ang = -6.283185307179586f * (float)u / 4096.0f;
        float s, co;
        sincosf(ang, &s, &co);
        twr[u] = co;
        twi[u] = s;
    }
    // load input in bit-reversed order (12-bit reverse)
    const float* xp = x + (size_t)b * T_LEN * C_DIM + c;
    for (int e = tid; e < 4096; e += 256) {
        int r = (int)(__brev((unsigned)e) >> 20);
        re[r] = xp[(size_t)e * C_DIM];
        im[e] = 0.0f;
    }
    __syncthreads();

    for (int s = 1; s <= 12; s++) {
        const int half = 1 << (s - 1);
        const int shift = 12 - s;
        for (int j = tid; j < 2048; j += 256) {
            int p = j & (half - 1);
            int g = j >> (s - 1);
            int i1 = (g << s) + p;
            int i2 = i1 + half;
            float wr = twr[p << shift];
            float wi = twi[p << shift];
            float r2 = re[i2], q2 = im[i2];
            float tr = wr * r2 - wi * q2;
            float ti = wr * q2 + wi * r2;
            float r1 = re[i1], q1 = im[i1];
            re[i2] = r1 - tr;
            im[i2] = q1 - ti;
            re[i1] = r1 + tr;
            im[i1] = q1 + ti;
        }
        __syncthreads();
    }

    float* mp = mags + ((size_t)(b * C_DIM + c)) * 2048;
    for (int u = tid; u < 2048; u += 256) {
        int f = u + 1;  // drop DC, bins 1..2048
        mp[u] = sqrtf(re[f] * re[f] + im[f] * im[f]);
    }
}

// ------------------------------------------------------------------
// amps[b][u] = mean over c of mags[b][c][u]   (deterministic order)
// ------------------------------------------------------------------
__global__ __launch_bounds__(256) void reduce_amps_kernel(const float* __restrict__ mags,
                                                          float* __restrict__ amps) {
    const int b = blockIdx.y;
    const int u = blockIdx.x * 256 + threadIdx.x;
    const float* mp = mags + (size_t)b * C_DIM * 2048 + u;
    float s = 0.0f;
    for (int c = 0; c < C_DIM; c++) s += mp[(size_t)c * 2048];
    amps[b * 2048 + u] = s * (1.0f / (float)C_DIM);
}

// ------------------------------------------------------------------
// Per-batch top-4 (value desc, ties -> lower index), periods, softmax w
// ------------------------------------------------------------------
__global__ __launch_bounds__(256) void topk_kernel(const float* __restrict__ amps,
                                                   int* __restrict__ meta_p,
                                                   float* __restrict__ meta_w) {
    const int b = blockIdx.x;
    const int tid = threadIdx.x;
    __shared__ float v[2048];
    __shared__ float rv[256];
    __shared__ int ri[256];
    __shared__ float topv[K_TOP];
    __shared__ int topi[K_TOP];

    for (int u = tid; u < 2048; u += 256) v[u] = amps[b * 2048 + u];

    for (int k = 0; k < K_TOP; k++) {
        __syncthreads();
        float bv = -1e30f;
        int bi = 2048;
        for (int u = tid; u < 2048; u += 256) {
            float val = v[u];
            if (val > bv) { bv = val; bi = u; }  // ascending scan keeps lowest idx on tie
        }
        rv[tid] = bv;
        ri[tid] = bi;
        __syncthreads();
        for (int s = 128; s > 0; s >>= 1) {
            if (tid < s) {
                float ov = rv[tid + s];
                int oi = ri[tid + s];
                if (ov > rv[tid] || (ov == rv[tid] && oi < ri[tid])) {
                    rv[tid] = ov;
                    ri[tid] = oi;
                }
            }
            __syncthreads();
        }
        if (tid == 0) {
            topv[k] = rv[0];
            topi[k] = ri[0];
            v[ri[0]] = -1e30f;
        }
    }
    __syncthreads();
    if (tid == 0) {
        float mx = topv[0];
        for (int k = 1; k < K_TOP; k++) mx = fmaxf(mx, topv[k]);
        float e[K_TOP], se = 0.0f;
        for (int k = 0; k < K_TOP; k++) { e[k] = expf(topv[k] - mx); se += e[k]; }
        for (int k = 0; k < K_TOP; k++) {
            int idx = topi[k];
            int d = (idx >= 1) ? idx : 1;
            int p = T_LEN / d;
            if (p < 1) p = 1;
            meta_p[b * K_TOP + k] = p;
            meta_w[b * K_TOP + k] = e[k] / se;
        }
    }
}

// ------------------------------------------------------------------
// Conv 3x3 (SAME, masked fold geometry) + bias + exact GELU, unfolded
// directly into convbuf[b][t][c].  One block: 8 timesteps x 256 c_out.
// LDS stages the 9-neighbor input vectors in ci-chunks of 128:
//   g[q][ci(128)][tt(8)]  -> broadcast ds_read_b128 in the main loop.
// ------------------------------------------------------------------
__global__ __launch_bounds__(256) void conv_kernel(const float* __restrict__ x,
                                                   const float* __restrict__ Wc,
                                                   const float* __restrict__ bc,
                                                   const int* __restrict__ meta_p,
                                                   float* __restrict__ convbuf,
                                                   int k) {
    const int b = blockIdx.y;
    const int n = meta_p[b * K_TOP + k];
    const int m = (T_LEN + n - 1) / n;
    const int t0 = blockIdx.x * 8;
    const int tid = threadIdx.x;

    __shared__ __align__(16) float g[9 * 128 * 8];  // 36 KB

    int i8[8], j8[8];
#pragma unroll
    for (int tt = 0; tt < 8; tt++) {
        int t = t0 + tt;
        int ii = t / n;
        i8[tt] = ii;
        j8[tt] = t - ii * n;
    }

    float acc[8] = {0.f, 0.f, 0.f, 0.f, 0.f, 0.f, 0.f, 0.f};
    const float* Wcp = Wc + tid;  // c_out = tid

    for (int cc = 0; cc < 2; cc++) {
        __syncthreads();  // protect g from previous chunk's readers
        {
            const int ci = tid & 127;
            const int pr = tid >> 7;
            for (int vq = pr; vq < 72; vq += 2) {
                int q = vq >> 3;
                int tt = vq & 7;
                int di = q / 3 - 1;
                int dj = q % 3 - 1;
                int ii = i8[tt] + di;
                int jj = j8[tt] + dj;
                float val = 0.0f;
                if (ii >= 0 && jj >= 0 && jj < n && ii < m) {
                    int tp = ii * n + jj;
                    if (tp < T_LEN)
                        val = x[((size_t)(b * T_LEN) + tp) * C_DIM + cc * 128 + ci];
                }
                g[(q * 128 + ci) * 8 + tt] = val;
            }
        }
        __syncthreads();

        for (int q = 0; q < 9; q++) {
            const float* wq = Wcp + (size_t)(q * C_DIM + cc * 128) * C_DIM;
            const float* gq = &g[q * 128 * 8];
#pragma unroll 4
            for (int ci2 = 0; ci2 < 128; ci2++) {
                float av[8];
                *(float4*)&av[0] = *(const float4*)&gq[ci2 * 8];
                *(float4*)&av[4] = *(const float4*)&gq[ci2 * 8 + 4];
                float wv = wq[(size_t)ci2 * C_DIM];
#pragma unroll
                for (int rr = 0; rr < 8; rr++) acc[rr] += av[rr] * wv;
            }
        }
    }

    const float bias = bc[tid];
    float* op = convbuf + ((size_t)(b * T_LEN) + t0) * C_DIM + tid;
#pragma unroll
    for (int tt = 0; tt < 8; tt++) {
        float y = acc[tt] + bias;
        op[(size_t)tt * C_DIM] = gelu_exact(y);
    }
}

// ------------------------------------------------------------------
// FeedForward for one k: h = gelu(row@W1+b1)@W2+b2 ; out += w_k * h
// Block: 16 rows x 256 threads. A[256ci][16r] and H[1024h][16r] in LDS,
// broadcast float4 reads in both GEMV phases.
// ------------------------------------------------------------------
__global__ __launch_bounds__(256) void ff_kernel(const float* __restrict__ convbuf,
                                                 const float* __restrict__ W1,
                                                 const float* __restrict__ b1,
                                                 const float* __restrict__ W2,
                                                 const float* __restrict__ b2,
                                                 const float* __restrict__ meta_w,
                                                 float* __restrict__ out,
                                                 int k) {
    __shared__ __align__(16) float A[256 * 16];   // 16 KB
    __shared__ __align__(16) float H[1024 * 16];  // 64 KB
    const int tid = threadIdx.x;
    const int row0 = blockIdx.x * 16;
    const int b = row0 >> 12;       // / 4096
    const int t0 = row0 & 4095;
    const float wk = meta_w[b * K_TOP + k];

    const float* src = convbuf + ((size_t)b * T_LEN + t0) * C_DIM;
#pragma unroll
    for (int r = 0; r < 16; r++) A[tid * 16 + r] = src[(size_t)r * C_DIM + tid];
    __syncthreads();

    // phase 1: hidden = gelu(A^T @ W1 + b1); thread owns h = tid + 256*hj
    float acc[4][16];
#pragma unroll
    for (int hj = 0; hj < 4; hj++)
#pragma unroll
        for (int rr = 0; rr < 16; rr++) acc[hj][rr] = 0.0f;

    const float* W1p = W1 + tid;
    for (int ci = 0; ci < 256; ci++) {
        float af[16];
        *(float4*)&af[0]  = *(const float4*)&A[ci * 16 + 0];
        *(float4*)&af[4]  = *(const float4*)&A[ci * 16 + 4];
        *(float4*)&af[8]  = *(const float4*)&A[ci * 16 + 8];
        *(float4*)&af[12] = *(const float4*)&A[ci * 16 + 12];
#pragma unroll
        for (int hj = 0; hj < 4; hj++) {
            float wv = W1p[(size_t)ci * 1024 + 256 * hj];
#pragma unroll
            for (int rr = 0; rr < 16; rr++) acc[hj][rr] += af[rr] * wv;
        }
    }
#pragma unroll
    for (int hj = 0; hj < 4; hj++) {
        int h = tid + 256 * hj;
        float bb = b1[h];
#pragma unroll
        for (int rr = 0; rr < 16; rr++) H[h * 16 + rr] = gelu_exact(acc[hj][rr] + bb);
    }
    __syncthreads();

    // phase 2: out_c = H^T @ W2 + b2 ; thread owns c_out = tid
    float acc2[16];
#pragma unroll
    for (int rr = 0; rr < 16; rr++) acc2[rr] = 0.0f;
    const float* W2p = W2 + tid;
    for (int hi = 0; hi < 1024; hi++) {
        float hf[16];
        *(float4*)&hf[0]  = *(const float4*)&H[hi * 16 + 0];
        *(float4*)&hf[4]  = *(const float4*)&H[hi * 16 + 4];
        *(float4*)&hf[8]  = *(const float4*)&H[hi * 16 + 8];
        *(float4*)&hf[12] = *(const float4*)&H[hi * 16 + 12];
        float wv = W2p[(size_t)hi * C_DIM];
#pragma unroll
        for (int rr = 0; rr < 16; rr++) acc2[rr] += hf[rr] * wv;
    }

    const float bb2 = b2[tid];
    float* op = out + ((size_t)b * T_LEN + t0) * C_DIM + tid;
#pragma unroll
    for (int rr = 0; rr < 16; rr++) op[(size_t)rr * C_DIM] += wk * (acc2[rr] + bb2);
}

// ------------------------------------------------------------------
extern "C" void kernel_launch(void* const* d_in, const int* in_sizes, int n_in,
                              void* d_out, int out_size, void* d_ws, size_t ws_size,
                              hipStream_t stream) {
    const float* x  = (const float*)d_in[0];
    const float* Wc = (const float*)d_in[1];
    const float* bc = (const float*)d_in[2];
    const float* W1 = (const float*)d_in[3];
    const float* b1 = (const float*)d_in[4];
    const float* W2 = (const float*)d_in[5];
    const float* b2 = (const float*)d_in[6];
    float* out = (float*)d_out;

    // workspace carve (all fp32):
    float* mags = (float*)d_ws;                                    // 8*256*2048   = 16 MB
    float* amps = mags + (size_t)B_DIM * C_DIM * 2048;             // 8*2048
    int* meta_p = (int*)(amps + B_DIM * 2048);                     // 32 ints
    float* meta_w = (float*)(meta_p + B_DIM * K_TOP);              // 32 floats
    float* convbuf = meta_w + B_DIM * K_TOP;                       // 8*4096*256   = 33.5 MB

    // 1. out = x
    copy_x_kernel<<<dim3((B_DIM * T_LEN * C_DIM / 4) / 256), 256, 0, stream>>>(
        (const float4*)x, (float4*)out);

    // 2. FFT magnitudes per (b,c)
    fft_mag_kernel<<<dim3(B_DIM * C_DIM), 256, 0, stream>>>(x, mags);

    // 3. channel-mean -> amps[b][2048]
    reduce_amps_kernel<<<dim3(2048 / 256, B_DIM), 256, 0, stream>>>(mags, amps);

    // 4. top-4 + periods + softmax weights
    topk_kernel<<<dim3(B_DIM), 256, 0, stream>>>(amps, meta_p, meta_w);

    // 5. per-k: fold+conv+gelu+unfold, then FF accumulate into out
    for (int k = 0; k < K_TOP; k++) {
        conv_kernel<<<dim3(T_LEN / 8, B_DIM), 256, 0, stream>>>(x, Wc, bc, meta_p, convbuf, k);
        ff_kernel<<<dim3(B_DIM * T_LEN / 16), 256, 0, stream>>>(convbuf, W1, b1, W2, b2,
                                                                meta_w, out, k);
    }
}

// Round 2
// 5450.394 us; speedup vs baseline: 1.0010x; 1.0010x over previous
//
#include <hip/hip_runtime.h>
#include <cstdint>
#include <cstddef>

#define T_LEN 4096
#define C_DIM 256
#define B_DIM 8
#define K_TOP 4

__device__ __forceinline__ float gelu_exact(float x) {
    return 0.5f * x * (1.0f + erff(x * 0.70710678118654752f));
}

// ------------------------------------------------------------------
// out = x   (fp32, float4 vectorized)
// ------------------------------------------------------------------
__global__ __launch_bounds__(256) void copy_x_kernel(const float4* __restrict__ x,
                                                     float4* __restrict__ out) {
    size_t i = (size_t)blockIdx.x * 256 + threadIdx.x;
    out[i] = x[i];
}

// ------------------------------------------------------------------
// Per-(b,c) 4096-pt radix-2 DIT FFT in LDS; write |X_f| for f=1..2048
// mags layout: [b][c][2048]  (coalesced writes, coalesced reduce reads)
// ------------------------------------------------------------------
__global__ __launch_bounds__(256) void fft_mag_kernel(const float* __restrict__ x,
                                                      float* __restrict__ mags) {
    const int bx = blockIdx.x;
    const int b = bx >> 8;
    const int c = bx & 255;
    const int tid = threadIdx.x;

    __shared__ __align__(16) float re[4096];
    __shared__ __align__(16) float im[4096];
    __shared__ __align__(16) float twr[2048];
    __shared__ __align__(16) float twi[2048];

    // twiddle table: W[u] = exp(-2*pi*i*u/4096)
    for (int u = tid; u < 2048; u += 256) {
        float ang = -6.283185307179586f * (float)u / 4096.0f;
        float s, co;
        sincosf(ang, &s, &co);
        twr[u] = co;
        twi[u] = s;
    }
    // load input in bit-reversed order (12-bit reverse)
    const float* xp = x + (size_t)b * T_LEN * C_DIM + c;
    for (int e = tid; e < 4096; e += 256) {
        int r = (int)(__brev((unsigned)e) >> 20);
        re[r] = xp[(size_t)e * C_DIM];
        im[e] = 0.0f;
    }
    __syncthreads();

    for (int s = 1; s <= 12; s++) {
        const int half = 1 << (s - 1);
        const int shift = 12 - s;
        for (int j = tid; j < 2048; j += 256) {
            int p = j & (half - 1);
            int g = j >> (s - 1);
            int i1 = (g << s) + p;
            int i2 = i1 + half;
            float wr = twr[p << shift];
            float wi = twi[p << shift];
            float r2 = re[i2], q2 = im[i2];
            float tr = wr * r2 - wi * q2;
            float ti = wr * q2 + wi * r2;
            float r1 = re[i1], q1 = im[i1];
            re[i2] = r1 - tr;
            im[i2] = q1 - ti;
            re[i1] = r1 + tr;
            im[i1] = q1 + ti;
        }
        __syncthreads();
    }

    float* mp = mags + ((size_t)(b * C_DIM + c)) * 2048;
    for (int u = tid; u < 2048; u += 256) {
        int f = u + 1;  // drop DC, bins 1..2048
        mp[u] = sqrtf(re[f] * re[f] + im[f] * im[f]);
    }
}

// ------------------------------------------------------------------
// amps[b][u] = mean over c of mags[b][c][u]   (deterministic order)
// ------------------------------------------------------------------
__global__ __launch_bounds__(256) void reduce_amps_kernel(const float* __restrict__ mags,
                                                          float* __restrict__ amps) {
    const int b = blockIdx.y;
    const int u = blockIdx.x * 256 + threadIdx.x;
    const float* mp = mags + (size_t)b * C_DIM * 2048 + u;
    float s = 0.0f;
    for (int c = 0; c < C_DIM; c++) s += mp[(size_t)c * 2048];
    amps[b * 2048 + u] = s * (1.0f / (float)C_DIM);
}

// ------------------------------------------------------------------
// Per-batch top-4 (value desc, ties -> lower index), periods, softmax w
// ------------------------------------------------------------------
__global__ __launch_bounds__(256) void topk_kernel(const float* __restrict__ amps,
                                                   int* __restrict__ meta_p,
                                                   float* __restrict__ meta_w) {
    const int b = blockIdx.x;
    const int tid = threadIdx.x;
    __shared__ float v[2048];
    __shared__ float rv[256];
    __shared__ int ri[256];
    __shared__ float topv[K_TOP];
    __shared__ int topi[K_TOP];

    for (int u = tid; u < 2048; u += 256) v[u] = amps[b * 2048 + u];

    for (int k = 0; k < K_TOP; k++) {
        __syncthreads();
        float bv = -1e30f;
        int bi = 2048;
        for (int u = tid; u < 2048; u += 256) {
            float val = v[u];
            if (val > bv) { bv = val; bi = u; }  // ascending scan keeps lowest idx on tie
        }
        rv[tid] = bv;
        ri[tid] = bi;
        __syncthreads();
        for (int s = 128; s > 0; s >>= 1) {
            if (tid < s) {
                float ov = rv[tid + s];
                int oi = ri[tid + s];
                if (ov > rv[tid] || (ov == rv[tid] && oi < ri[tid])) {
                    rv[tid] = ov;
                    ri[tid] = oi;
                }
            }
            __syncthreads();
        }
        if (tid == 0) {
            topv[k] = rv[0];
            topi[k] = ri[0];
            v[ri[0]] = -1e30f;
        }
    }
    __syncthreads();
    if (tid == 0) {
        float mx = topv[0];
        for (int k = 1; k < K_TOP; k++) mx = fmaxf(mx, topv[k]);
        float e[K_TOP], se = 0.0f;
        for (int k = 0; k < K_TOP; k++) { e[k] = expf(topv[k] - mx); se += e[k]; }
        for (int k = 0; k < K_TOP; k++) {
            int idx = topi[k];
            int d = (idx >= 1) ? idx : 1;
            int p = T_LEN / d;
            if (p < 1) p = 1;
            meta_p[b * K_TOP + k] = p;
            meta_w[b * K_TOP + k] = e[k] / se;
        }
    }
}

// ------------------------------------------------------------------
// Conv 3x3 (SAME, masked fold geometry) + bias + exact GELU, unfolded
// directly into convbuf[b][t][c].  One block: 8 timesteps x 256 c_out.
// LDS stages the 9-neighbor input vectors in ci-chunks of 128:
//   g[q][ci(128)][tt(8)]  -> broadcast ds_read_b128 in the main loop.
// ------------------------------------------------------------------
__global__ __launch_bounds__(256) void conv_kernel(const float* __restrict__ x,
                                                   const float* __restrict__ Wc,
                                                   const float* __restrict__ bc,
                                                   const int* __restrict__ meta_p,
                                                   float* __restrict__ convbuf,
                                                   int k) {
    const int b = blockIdx.y;
    const int n = meta_p[b * K_TOP + k];
    const int m = (T_LEN + n - 1) / n;
    const int t0 = blockIdx.x * 8;
    const int tid = threadIdx.x;

    __shared__ __align__(16) float g[9 * 128 * 8];  // 36 KB

    int i8[8], j8[8];
#pragma unroll
    for (int tt = 0; tt < 8; tt++) {
        int t = t0 + tt;
        int ii = t / n;
        i8[tt] = ii;
        j8[tt] = t - ii * n;
    }

    float acc[8] = {0.f, 0.f, 0.f, 0.f, 0.f, 0.f, 0.f, 0.f};
    const float* Wcp = Wc + tid;  // c_out = tid

    for (int cc = 0; cc < 2; cc++) {
        __syncthreads();  // protect g from previous chunk's readers
        {
            const int ci = tid & 127;
            const int pr = tid >> 7;
            for (int vq = pr; vq < 72; vq += 2) {
                int q = vq >> 3;
                int tt = vq & 7;
                int di = q / 3 - 1;
                int dj = q % 3 - 1;
                int ii = i8[tt] + di;
                int jj = j8[tt] + dj;
                float val = 0.0f;
                if (ii >= 0 && jj >= 0 && jj < n && ii < m) {
                    int tp = ii * n + jj;
                    if (tp < T_LEN)
                        val = x[((size_t)(b * T_LEN) + tp) * C_DIM + cc * 128 + ci];
                }
                g[(q * 128 + ci) * 8 + tt] = val;
            }
        }
        __syncthreads();

        for (int q = 0; q < 9; q++) {
            const float* wq = Wcp + (size_t)(q * C_DIM + cc * 128) * C_DIM;
            const float* gq = &g[q * 128 * 8];
#pragma unroll 4
            for (int ci2 = 0; ci2 < 128; ci2++) {
                float av[8];
                *(float4*)&av[0] = *(const float4*)&gq[ci2 * 8];
                *(float4*)&av[4] = *(const float4*)&gq[ci2 * 8 + 4];
                float wv = wq[(size_t)ci2 * C_DIM];
#pragma unroll
                for (int rr = 0; rr < 8; rr++) acc[rr] += av[rr] * wv;
            }
        }
    }

    const float bias = bc[tid];
    float* op = convbuf + ((size_t)(b * T_LEN) + t0) * C_DIM + tid;
#pragma unroll
    for (int tt = 0; tt < 8; tt++) {
        float y = acc[tt] + bias;
        op[(size_t)tt * C_DIM] = gelu_exact(y);
    }
}

// ------------------------------------------------------------------
// FeedForward for one k: h = gelu(row@W1+b1)@W2+b2 ; out += w_k * h
// Block: 16 rows x 256 threads. A[256ci][16r] and H[1024h][16r] in LDS,
// broadcast float4 reads in both GEMV phases.
// ------------------------------------------------------------------
__global__ __launch_bounds__(256) void ff_kernel(const float* __restrict__ convbuf,
                                                 const float* __restrict__ W1,
                                                 const float* __restrict__ b1,
                                                 const float* __restrict__ W2,
                                                 const float* __restrict__ b2,
                                                 const float* __restrict__ meta_w,
                                                 float* __restrict__ out,
                                                 int k) {
    __shared__ __align__(16) float A[256 * 16];   // 16 KB
    __shared__ __align__(16) float H[1024 * 16];  // 64 KB
    const int tid = threadIdx.x;
    const int row0 = blockIdx.x * 16;
    const int b = row0 >> 12;       // / 4096
    const int t0 = row0 & 4095;
    const float wk = meta_w[b * K_TOP + k];

    const float* src = convbuf + ((size_t)b * T_LEN + t0) * C_DIM;
#pragma unroll
    for (int r = 0; r < 16; r++) A[tid * 16 + r] = src[(size_t)r * C_DIM + tid];
    __syncthreads();

    // phase 1: hidden = gelu(A^T @ W1 + b1); thread owns h = tid + 256*hj
    float acc[4][16];
#pragma unroll
    for (int hj = 0; hj < 4; hj++)
#pragma unroll
        for (int rr = 0; rr < 16; rr++) acc[hj][rr] = 0.0f;

    const float* W1p = W1 + tid;
    for (int ci = 0; ci < 256; ci++) {
        float af[16];
        *(float4*)&af[0]  = *(const float4*)&A[ci * 16 + 0];
        *(float4*)&af[4]  = *(const float4*)&A[ci * 16 + 4];
        *(float4*)&af[8]  = *(const float4*)&A[ci * 16 + 8];
        *(float4*)&af[12] = *(const float4*)&A[ci * 16 + 12];
#pragma unroll
        for (int hj = 0; hj < 4; hj++) {
            float wv = W1p[(size_t)ci * 1024 + 256 * hj];
#pragma unroll
            for (int rr = 0; rr < 16; rr++) acc[hj][rr] += af[rr] * wv;
        }
    }
#pragma unroll
    for (int hj = 0; hj < 4; hj++) {
        int h = tid + 256 * hj;
        float bb = b1[h];
#pragma unroll
        for (int rr = 0; rr < 16; rr++) H[h * 16 + rr] = gelu_exact(acc[hj][rr] + bb);
    }
    __syncthreads();

    // phase 2: out_c = H^T @ W2 + b2 ; thread owns c_out = tid
    float acc2[16];
#pragma unroll
    for (int rr = 0; rr < 16; rr++) acc2[rr] = 0.0f;
    const float* W2p = W2 + tid;
    for (int hi = 0; hi < 1024; hi++) {
        float hf[16];
        *(float4*)&hf[0]  = *(const float4*)&H[hi * 16 + 0];
        *(float4*)&hf[4]  = *(const float4*)&H[hi * 16 + 4];
        *(float4*)&hf[8]  = *(const float4*)&H[hi * 16 + 8];
        *(float4*)&hf[12] = *(const float4*)&H[hi * 16 + 12];
        float wv = W2p[(size_t)hi * C_DIM];
#pragma unroll
        for (int rr = 0; rr < 16; rr++) acc2[rr] += hf[rr] * wv;
    }

    const float bb2 = b2[tid];
    float* op = out + ((size_t)b * T_LEN + t0) * C_DIM + tid;
#pragma unroll
    for (int rr = 0; rr < 16; rr++) op[(size_t)rr * C_DIM] += wk * (acc2[rr] + bb2);
}

// ------------------------------------------------------------------
extern "C" void kernel_launch(void* const* d_in, const int* in_sizes, int n_in,
                              void* d_out, int out_size, void* d_ws, size_t ws_size,
                              hipStream_t stream) {
    const float* x  = (const float*)d_in[0];
    const float* Wc = (const float*)d_in[1];
    const float* bc = (const float*)d_in[2];
    const float* W1 = (const float*)d_in[3];
    const float* b1 = (const float*)d_in[4];
    const float* W2 = (const float*)d_in[5];
    const float* b2 = (const float*)d_in[6];
    float* out = (float*)d_out;

    // workspace carve (all fp32):
    float* mags = (float*)d_ws;                                    // 8*256*2048   = 16 MB
    float* amps = mags + (size_t)B_DIM * C_DIM * 2048;             // 8*2048
    int* meta_p = (int*)(amps + B_DIM * 2048);                     // 32 ints
    float* meta_w = (float*)(meta_p + B_DIM * K_TOP);              // 32 floats
    float* convbuf = meta_w + B_DIM * K_TOP;                       // 8*4096*256   = 33.5 MB

    // 1. out = x
    copy_x_kernel<<<dim3((B_DIM * T_LEN * C_DIM / 4) / 256), 256, 0, stream>>>(
        (const float4*)x, (float4*)out);

    // 2. FFT magnitudes per (b,c)
    fft_mag_kernel<<<dim3(B_DIM * C_DIM), 256, 0, stream>>>(x, mags);

    // 3. channel-mean -> amps[b][2048]
    reduce_amps_kernel<<<dim3(2048 / 256, B_DIM), 256, 0, stream>>>(mags, amps);

    // 4. top-4 + periods + softmax weights
    topk_kernel<<<dim3(B_DIM), 256, 0, stream>>>(amps, meta_p, meta_w);

    // 5. per-k: fold+conv+gelu+unfold, then FF accumulate into out
    for (int k = 0; k < K_TOP; k++) {
        conv_kernel<<<dim3(T_LEN / 8, B_DIM), 256, 0, stream>>>(x, Wc, bc, meta_p, convbuf, k);
        ff_kernel<<<dim3(B_DIM * T_LEN / 16), 256, 0, stream>>>(convbuf, W1, b1, W2, b2,
                                                                meta_w, out, k);
    }
}